// Round 1
// baseline (364.760 us; speedup 1.0000x reference)
//
#include <hip/hip_runtime.h>

typedef __attribute__((ext_vector_type(4))) float f32x4;
typedef __attribute__((ext_vector_type(8))) short short8;
typedef __attribute__((ext_vector_type(8))) unsigned short u16x8;
typedef __attribute__((ext_vector_type(4))) unsigned short u16x4;

#define D_MODEL 1024
#define NHEADS 16
#define T_SEQ 2048
#define M_TOT 4096   // B*T

__device__ __forceinline__ unsigned short f2bf(float f) {
    union { float f; unsigned int u; } v; v.f = f;
    return (unsigned short)((v.u + 0x7fffu + ((v.u >> 16) & 1u)) >> 16);
}

// ---------------- convert x fp32 -> bf16 ----------------
__global__ __launch_bounds__(256) void convert_x_kernel(const float* __restrict__ X,
                                                        unsigned short* __restrict__ Xb) {
    const int i = (blockIdx.x * 256 + threadIdx.x) * 4;
    const float4 v = *(const float4*)(X + i);
    u16x4 r;
    r.x = f2bf(v.x); r.y = f2bf(v.y); r.z = f2bf(v.z); r.w = f2bf(v.w);
    *(u16x4*)(Xb + i) = r;
}

// ---------------- W [k][n] fp32 -> Wt [n][k] bf16 (LDS-tiled transpose) ----------------
__global__ __launch_bounds__(256) void transpose_w_kernel(const float* __restrict__ W,
                                                          unsigned short* __restrict__ Wt) {
    __shared__ float tile[64][65];
    const int n0 = blockIdx.x * 64, k0 = blockIdx.y * 64;
    for (int i = threadIdx.x; i < 4096; i += 256) {
        const int r = i >> 6, c = i & 63;
        tile[r][c] = W[(size_t)(k0 + r) * D_MODEL + n0 + c];
    }
    __syncthreads();
    for (int i = threadIdx.x; i < 4096; i += 256) {
        const int r = i >> 6, c = i & 63;  // r: n-local, c: k-local
        Wt[(size_t)(n0 + r) * D_MODEL + k0 + c] = f2bf(tile[c][r]);
    }
}

// ---------------- GEMM: C = A[M][1024] @ W, with Wt[n][k] pre-transposed ----------------
// MI: 16-row m-tiles per wave (4 -> TM=128, 2 -> TM=64). TN fixed 128.
// OUTMODE 0: fp32 row-major C (out projection)
// OUTMODE 1: bf16 head-major [b][h][t][64] with RoPE for z<2 (q,k), plain for z==2 (v)
#define TN_G 128
#define BK_G 32
#define BKP_G 36   // padded LDS row (bf16 elems); (18m+4q)%32 distinct-ish -> conflict-free b128

template<int MI, int OUTMODE>
__global__ __launch_bounds__(256) void gemm_kernel(
    const unsigned short* __restrict__ A,
    const unsigned short* __restrict__ Bt0,
    void* __restrict__ Cout0,
    const float* __restrict__ cosp,
    const float* __restrict__ sinp)
{
    constexpr int TMc = MI * 32;
    constexpr int NA = (TMc * 4) / 256;   // u16x8 chunks per thread for A (2 or 1)
    __shared__ unsigned short sA[TMc * BKP_G];
    __shared__ unsigned short sB[TN_G * BKP_G];

    const int tid = threadIdx.x;
    const int wid = tid >> 6;
    const int lane = tid & 63;
    const int quad = lane >> 4;
    const int l16 = lane & 15;
    const int wm = wid >> 1, wn = wid & 1;
    const int m0 = blockIdx.x * TMc, n0 = blockIdx.y * TN_G;
    const int z = blockIdx.z;
    const unsigned short* Bt = Bt0 + (size_t)z * D_MODEL * D_MODEL;

    f32x4 acc[MI][4] = {};

    for (int k0 = 0; k0 < D_MODEL; k0 += BK_G) {
        u16x8 av[NA], bv[2];
        #pragma unroll
        for (int i = 0; i < NA; ++i) {
            const int c = tid + i * 256, r = c >> 2, sg = (c & 3) * 8;
            av[i] = *(const u16x8*)(A + (size_t)(m0 + r) * D_MODEL + k0 + sg);
        }
        #pragma unroll
        for (int i = 0; i < 2; ++i) {
            const int c = tid + i * 256, r = c >> 2, sg = (c & 3) * 8;
            bv[i] = *(const u16x8*)(Bt + (size_t)(n0 + r) * D_MODEL + k0 + sg);
        }
        __syncthreads();
        #pragma unroll
        for (int i = 0; i < NA; ++i) {
            const int c = tid + i * 256, r = c >> 2, sg = (c & 3) * 8;
            *(u16x8*)&sA[r * BKP_G + sg] = av[i];
        }
        #pragma unroll
        for (int i = 0; i < 2; ++i) {
            const int c = tid + i * 256, r = c >> 2, sg = (c & 3) * 8;
            *(u16x8*)&sB[r * BKP_G + sg] = bv[i];
        }
        __syncthreads();

        short8 af[MI], bf[4];
        #pragma unroll
        for (int i = 0; i < MI; ++i)
            af[i] = *(const short8*)&sA[(wm * (MI * 16) + i * 16 + l16) * BKP_G + quad * 8];
        #pragma unroll
        for (int i = 0; i < 4; ++i)
            bf[i] = *(const short8*)&sB[(wn * 64 + i * 16 + l16) * BKP_G + quad * 8];
        #pragma unroll
        for (int mi = 0; mi < MI; ++mi)
            #pragma unroll
            for (int ni = 0; ni < 4; ++ni)
                acc[mi][ni] = __builtin_amdgcn_mfma_f32_16x16x32_bf16(af[mi], bf[ni], acc[mi][ni], 0, 0, 0);
    }

    if constexpr (OUTMODE == 0) {
        float* C = (float*)Cout0;
        #pragma unroll
        for (int mi = 0; mi < MI; ++mi) {
            const int mb = m0 + wm * (MI * 16) + mi * 16 + quad * 4;
            #pragma unroll
            for (int ni = 0; ni < 4; ++ni) {
                const int n = n0 + wn * 64 + ni * 16 + l16;
                #pragma unroll
                for (int r = 0; r < 4; ++r)
                    C[(size_t)(mb + r) * D_MODEL + n] = acc[mi][ni][r];
            }
        }
    } else {
        unsigned short* O = (unsigned short*)Cout0 + (size_t)z * M_TOT * D_MODEL;
        const int h = (n0 + wn * 64) >> 6;   // each wave's 64 cols = exactly one head
        const int rope = (z < 2);
        #pragma unroll
        for (int mi = 0; mi < MI; ++mi) {
            #pragma unroll
            for (int r = 0; r < 4; ++r) {
                const int m = m0 + wm * (MI * 16) + mi * 16 + quad * 4 + r;
                const int b = m >> 11, t = m & (T_SEQ - 1);
                const size_t rowoff = ((size_t)(b * NHEADS + h) * T_SEQ + t) * 64;
                if (rope) {
                    #pragma unroll
                    for (int ni = 0; ni < 2; ++ni) {
                        const int d = ni * 16 + l16;           // 0..31
                        const float c = cosp[t * 32 + d], s = sinp[t * 32 + d];
                        const float x1 = acc[mi][ni][r], x2 = acc[mi][ni + 2][r];
                        O[rowoff + d]      = f2bf(x1 * c - x2 * s);
                        O[rowoff + d + 32] = f2bf(x1 * s + x2 * c);
                    }
                } else {
                    #pragma unroll
                    for (int ni = 0; ni < 4; ++ni)
                        O[rowoff + ni * 16 + l16] = f2bf(acc[mi][ni][r]);
                }
            }
        }
    }
}

// ---------------- flash attention (causal), bf16 MFMA, fp32 online softmax ----------------
#define LDA 66   // padded LDS row (bf16 elems): staging scatter 2-way (free), frag reads conflict-free

__global__ __launch_bounds__(256) void attn_kernel(
    const unsigned short* __restrict__ Q,   // [(b*16+h)][2048][64] bf16 (RoPE applied)
    const unsigned short* __restrict__ Kg,
    const unsigned short* __restrict__ Vg,
    unsigned short* __restrict__ Z)         // [4096][1024] bf16, n = h*64+d
{
    __shared__ unsigned short sK[64 * LDA];
    __shared__ unsigned short sVt[64 * LDA];
    __shared__ unsigned short sP[4][16 * LDA];

    const int tid = threadIdx.x;
    const int wid = tid >> 6;
    const int lane = tid & 63;
    const int quad = lane >> 4;
    const int l16 = lane & 15;
    const int q0 = blockIdx.x * 64;
    const int bh = blockIdx.y;
    const unsigned short* Qp = Q + (size_t)bh * T_SEQ * 64;
    const unsigned short* Kp = Kg + (size_t)bh * T_SEQ * 64;
    const unsigned short* Vp = Vg + (size_t)bh * T_SEQ * 64;

    // Q fragments (A-layout): row = q0+wid*16+l16, k = ks*32 + quad*8 + j
    short8 aq[2];
    {
        const unsigned short* qr = Qp + (size_t)(q0 + wid * 16 + l16) * 64 + quad * 8;
        aq[0] = *(const short8*)(qr);
        aq[1] = *(const short8*)(qr + 32);
    }
    float m_i[4], l_i[4];
    f32x4 o[4] = {};
    #pragma unroll
    for (int r = 0; r < 4; ++r) { m_i[r] = -1e30f; l_i[r] = 0.f; }

    const int qr_max = q0 + wid * 16 + 15;
    const int jmax = blockIdx.x;
    const int kr = tid >> 2, ksg = (tid & 3) * 16;

    for (int j = 0; j <= jmax; ++j) {
        // ---- stage K [kv][d] and V transposed [d][kv] ----
        const unsigned short* Ksrc = Kp + (size_t)(j * 64 + kr) * 64 + ksg;
        const u16x8 kv0 = *(const u16x8*)(Ksrc);
        const u16x8 kv1 = *(const u16x8*)(Ksrc + 8);
        u16x4 vv[4];
        #pragma unroll
        for (int it = 0; it < 4; ++it) {
            const int i4 = it * 256 + tid;
            vv[it] = *(const u16x4*)(Vp + (size_t)j * 64 * 64 + i4 * 4);
        }
        __syncthreads();
        *(u16x8*)&sK[kr * LDA + ksg] = kv0;
        *(u16x8*)&sK[kr * LDA + ksg + 8] = kv1;
        #pragma unroll
        for (int it = 0; it < 4; ++it) {
            const int i4 = it * 256 + tid;
            const int t_ = i4 >> 4;
            const int d0 = (i4 & 15) * 4;
            #pragma unroll
            for (int e = 0; e < 4; ++e)
                sVt[(d0 + e) * LDA + t_] = vv[it][e];
        }
        __syncthreads();

        if (j * 64 <= qr_max) {   // wave-uniform: skip fully-future kv tiles
            // S = Q K^T (16x64 per wave)
            f32x4 s[4] = {};
            #pragma unroll
            for (int nt = 0; nt < 4; ++nt) {
                const short8 kf0 = *(const short8*)&sK[(nt * 16 + l16) * LDA + quad * 8];
                const short8 kf1 = *(const short8*)&sK[(nt * 16 + l16) * LDA + 32 + quad * 8];
                s[nt] = __builtin_amdgcn_mfma_f32_16x16x32_bf16(aq[0], kf0, s[nt], 0, 0, 0);
                s[nt] = __builtin_amdgcn_mfma_f32_16x16x32_bf16(aq[1], kf1, s[nt], 0, 0, 0);
            }
            // scale + causal mask + row max (rows live at quad*4+r, cols across 16 lanes)
            float mloc[4] = {-1e30f, -1e30f, -1e30f, -1e30f};
            #pragma unroll
            for (int nt = 0; nt < 4; ++nt) {
                const int kvp = j * 64 + nt * 16 + l16;
                #pragma unroll
                for (int r = 0; r < 4; ++r) {
                    const int qrow = q0 + wid * 16 + quad * 4 + r;
                    float v = s[nt][r] * 0.125f;
                    v = (kvp <= qrow) ? v : -1e30f;
                    s[nt][r] = v;
                    mloc[r] = fmaxf(mloc[r], v);
                }
            }
            #pragma unroll
            for (int off = 8; off >= 1; off >>= 1)
                #pragma unroll
                for (int r = 0; r < 4; ++r)
                    mloc[r] = fmaxf(mloc[r], __shfl_xor(mloc[r], off));
            // online softmax update
            float rs[4] = {0.f, 0.f, 0.f, 0.f};
            #pragma unroll
            for (int r = 0; r < 4; ++r) {
                const float mnew = fmaxf(m_i[r], mloc[r]);
                const float al = __expf(m_i[r] - mnew);
                m_i[r] = mnew;
                l_i[r] *= al;
                #pragma unroll
                for (int dt = 0; dt < 4; ++dt) o[dt][r] *= al;
                #pragma unroll
                for (int nt = 0; nt < 4; ++nt) {
                    const float p = __expf(s[nt][r] - mnew);
                    s[nt][r] = p;
                    rs[r] += p;
                }
            }
            #pragma unroll
            for (int off = 8; off >= 1; off >>= 1)
                #pragma unroll
                for (int r = 0; r < 4; ++r)
                    rs[r] += __shfl_xor(rs[r], off);
            #pragma unroll
            for (int r = 0; r < 4; ++r) l_i[r] += rs[r];

            // P: C-layout -> A-layout via per-wave LDS round-trip
            unsigned short* Pw = &sP[wid][0];
            #pragma unroll
            for (int nt = 0; nt < 4; ++nt)
                #pragma unroll
                for (int r = 0; r < 4; ++r)
                    Pw[(quad * 4 + r) * LDA + nt * 16 + l16] = f2bf(s[nt][r]);
            asm volatile("s_waitcnt lgkmcnt(0)" ::: "memory");
            // O += P @ V
            #pragma unroll
            for (int ks = 0; ks < 2; ++ks) {
                const short8 pf = *(const short8*)&Pw[l16 * LDA + ks * 32 + quad * 8];
                #pragma unroll
                for (int dt = 0; dt < 4; ++dt) {
                    const short8 vf = *(const short8*)&sVt[(dt * 16 + l16) * LDA + ks * 32 + quad * 8];
                    o[dt] = __builtin_amdgcn_mfma_f32_16x16x32_bf16(pf, vf, o[dt], 0, 0, 0);
                }
            }
        }
    }
    // epilogue: normalize and write Z row-major [m][h*64+d]
    const int h = bh & 15, b = bh >> 4;
    #pragma unroll
    for (int dt = 0; dt < 4; ++dt)
        #pragma unroll
        for (int r = 0; r < 4; ++r) {
            const int qrow = q0 + wid * 16 + quad * 4 + r;
            const float val = o[dt][r] / l_i[r];
            Z[(size_t)(b * T_SEQ + qrow) * D_MODEL + h * 64 + dt * 16 + l16] = f2bf(val);
        }
}

// ---------------- launcher ----------------
extern "C" void kernel_launch(void* const* d_in, const int* in_sizes, int n_in,
                              void* d_out, int out_size, void* d_ws, size_t ws_size,
                              hipStream_t stream) {
    const float* x    = (const float*)d_in[0];
    const float* cosp = (const float*)d_in[1];
    const float* sinp = (const float*)d_in[2];
    const float* Wq   = (const float*)d_in[3];
    const float* Wk   = (const float*)d_in[4];
    const float* Wv   = (const float*)d_in[5];
    const float* Wo   = (const float*)d_in[6];

    char* w = (char*)d_ws;
    unsigned short* xb  = (unsigned short*)w; w += (size_t)M_TOT * D_MODEL * 2;    // 8 MB
    unsigned short* wtq = (unsigned short*)w; w += (size_t)D_MODEL * D_MODEL * 2;  // 2 MB
    unsigned short* wtk = (unsigned short*)w; w += (size_t)D_MODEL * D_MODEL * 2;
    unsigned short* wtv = (unsigned short*)w; w += (size_t)D_MODEL * D_MODEL * 2;
    unsigned short* wto = (unsigned short*)w; w += (size_t)D_MODEL * D_MODEL * 2;
    unsigned short* Qb  = (unsigned short*)w; w += (size_t)M_TOT * D_MODEL * 2;    // 8 MB
    unsigned short* Kb  = (unsigned short*)w; w += (size_t)M_TOT * D_MODEL * 2;
    unsigned short* Vb  = (unsigned short*)w; w += (size_t)M_TOT * D_MODEL * 2;
    unsigned short* Zb  = (unsigned short*)w; w += (size_t)M_TOT * D_MODEL * 2;

    convert_x_kernel<<<(M_TOT * D_MODEL) / 1024, 256, 0, stream>>>(x, xb);
    transpose_w_kernel<<<dim3(16, 16), 256, 0, stream>>>(Wq, wtq);
    transpose_w_kernel<<<dim3(16, 16), 256, 0, stream>>>(Wk, wtk);
    transpose_w_kernel<<<dim3(16, 16), 256, 0, stream>>>(Wv, wtv);
    transpose_w_kernel<<<dim3(16, 16), 256, 0, stream>>>(Wo, wto);

    // fused QKV projection + RoPE epilogue; z selects weight/output (wtq/wtk/wtv, Qb/Kb/Vb contiguous)
    gemm_kernel<4, 1><<<dim3(M_TOT / 128, D_MODEL / 128, 3), 256, 0, stream>>>(
        xb, wtq, (void*)Qb, cosp, sinp);

    attn_kernel<<<dim3(T_SEQ / 64, 32), 256, 0, stream>>>(Qb, Kb, Vb, Zb);

    // out projection -> fp32 d_out (TM=64 for 512 blocks / occupancy)
    gemm_kernel<2, 0><<<dim3(M_TOT / 64, D_MODEL / 128, 1), 256, 0, stream>>>(
        Zb, wto, d_out, nullptr, nullptr);
}

// Round 2
// 330.626 us; speedup vs baseline: 1.1032x; 1.1032x over previous
//
#include <hip/hip_runtime.h>

typedef __attribute__((ext_vector_type(4))) float f32x4;
typedef __attribute__((ext_vector_type(8))) short short8;
typedef __attribute__((ext_vector_type(8))) unsigned short u16x8;
typedef __attribute__((ext_vector_type(4))) unsigned short u16x4;

#define D_MODEL 1024
#define NHEADS 16
#define T_SEQ 2048
#define M_TOT 4096   // B*T

__device__ __forceinline__ unsigned short f2bf(float f) {
    union { float f; unsigned int u; } v; v.f = f;
    return (unsigned short)((v.u + 0x7fffu + ((v.u >> 16) & 1u)) >> 16);
}

// ---------------- convert x fp32 -> bf16 ----------------
__global__ __launch_bounds__(256) void convert_x_kernel(const float* __restrict__ X,
                                                        unsigned short* __restrict__ Xb) {
    const int i = (blockIdx.x * 256 + threadIdx.x) * 4;
    const float4 v = *(const float4*)(X + i);
    u16x4 r;
    r.x = f2bf(v.x); r.y = f2bf(v.y); r.z = f2bf(v.z); r.w = f2bf(v.w);
    *(u16x4*)(Xb + i) = r;
}

// ---------------- 4x W [k][n] fp32 -> Wt [n][k] bf16, batched over z ----------------
__global__ __launch_bounds__(256) void transpose_w_kernel(const float* __restrict__ W0,
                                                          const float* __restrict__ W1,
                                                          const float* __restrict__ W2,
                                                          const float* __restrict__ W3,
                                                          unsigned short* __restrict__ Wt0) {
    __shared__ float tile[64][65];
    const int z = blockIdx.z;
    const float* W = (z == 0) ? W0 : (z == 1) ? W1 : (z == 2) ? W2 : W3;
    unsigned short* Wt = Wt0 + (size_t)z * D_MODEL * D_MODEL;
    const int n0 = blockIdx.x * 64, k0 = blockIdx.y * 64;
    for (int i = threadIdx.x; i < 4096; i += 256) {
        const int r = i >> 6, c = i & 63;
        tile[r][c] = W[(size_t)(k0 + r) * D_MODEL + n0 + c];
    }
    __syncthreads();
    for (int i = threadIdx.x; i < 4096; i += 256) {
        const int r = i >> 6, c = i & 63;  // r: n-local, c: k-local
        Wt[(size_t)(n0 + r) * D_MODEL + k0 + c] = f2bf(tile[c][r]);
    }
}

// ---------------- GEMM: C = A[M][1024] @ W, with Wt[n][k] pre-transposed ----------------
// OUTMODE 0: fp32 row-major C (out projection)
// OUTMODE 1: z=0 Q (RoPE, pre-scaled 0.125), z=1 K (RoPE), z=2 V (transposed [bh][d][t])
#define TN_G 128
#define BK_G 32
#define BKP_G 36

template<int MI, int OUTMODE>
__global__ __launch_bounds__(256) void gemm_kernel(
    const unsigned short* __restrict__ A,
    const unsigned short* __restrict__ Bt0,
    void* __restrict__ Cout0,
    const float* __restrict__ cosp,
    const float* __restrict__ sinp)
{
    constexpr int TMc = MI * 32;
    constexpr int NA = (TMc * 4) / 256;
    __shared__ unsigned short sA[TMc * BKP_G];
    __shared__ unsigned short sB[TN_G * BKP_G];

    const int tid = threadIdx.x;
    const int wid = tid >> 6;
    const int lane = tid & 63;
    const int quad = lane >> 4;
    const int l16 = lane & 15;
    const int wm = wid >> 1, wn = wid & 1;
    const int m0 = blockIdx.x * TMc, n0 = blockIdx.y * TN_G;
    const int z = blockIdx.z;
    const unsigned short* Bt = Bt0 + (size_t)z * D_MODEL * D_MODEL;

    f32x4 acc[MI][4] = {};

    for (int k0 = 0; k0 < D_MODEL; k0 += BK_G) {
        u16x8 av[NA], bv[2];
        #pragma unroll
        for (int i = 0; i < NA; ++i) {
            const int c = tid + i * 256, r = c >> 2, sg = (c & 3) * 8;
            av[i] = *(const u16x8*)(A + (size_t)(m0 + r) * D_MODEL + k0 + sg);
        }
        #pragma unroll
        for (int i = 0; i < 2; ++i) {
            const int c = tid + i * 256, r = c >> 2, sg = (c & 3) * 8;
            bv[i] = *(const u16x8*)(Bt + (size_t)(n0 + r) * D_MODEL + k0 + sg);
        }
        __syncthreads();
        #pragma unroll
        for (int i = 0; i < NA; ++i) {
            const int c = tid + i * 256, r = c >> 2, sg = (c & 3) * 8;
            *(u16x8*)&sA[r * BKP_G + sg] = av[i];
        }
        #pragma unroll
        for (int i = 0; i < 2; ++i) {
            const int c = tid + i * 256, r = c >> 2, sg = (c & 3) * 8;
            *(u16x8*)&sB[r * BKP_G + sg] = bv[i];
        }
        __syncthreads();

        short8 af[MI], bf[4];
        #pragma unroll
        for (int i = 0; i < MI; ++i)
            af[i] = *(const short8*)&sA[(wm * (MI * 16) + i * 16 + l16) * BKP_G + quad * 8];
        #pragma unroll
        for (int i = 0; i < 4; ++i)
            bf[i] = *(const short8*)&sB[(wn * 64 + i * 16 + l16) * BKP_G + quad * 8];
        #pragma unroll
        for (int mi = 0; mi < MI; ++mi)
            #pragma unroll
            for (int ni = 0; ni < 4; ++ni)
                acc[mi][ni] = __builtin_amdgcn_mfma_f32_16x16x32_bf16(af[mi], bf[ni], acc[mi][ni], 0, 0, 0);
    }

    if constexpr (OUTMODE == 0) {
        float* C = (float*)Cout0;
        #pragma unroll
        for (int mi = 0; mi < MI; ++mi) {
            const int mb = m0 + wm * (MI * 16) + mi * 16 + quad * 4;
            #pragma unroll
            for (int ni = 0; ni < 4; ++ni) {
                const int n = n0 + wn * 64 + ni * 16 + l16;
                #pragma unroll
                for (int r = 0; r < 4; ++r)
                    C[(size_t)(mb + r) * D_MODEL + n] = acc[mi][ni][r];
            }
        }
    } else {
        unsigned short* O = (unsigned short*)Cout0 + (size_t)z * M_TOT * D_MODEL;
        const int h = (n0 + wn * 64) >> 6;   // each wave's 64 cols = exactly one head
        if (z == 2) {
            // V: write transposed Vt[bh][d][t], packed u16x4 over 4 consecutive t
            #pragma unroll
            for (int mi = 0; mi < MI; ++mi) {
                const int mb = m0 + wm * (MI * 16) + mi * 16 + quad * 4;
                const int b = mb >> 11, t = mb & (T_SEQ - 1);
                #pragma unroll
                for (int ni = 0; ni < 4; ++ni) {
                    const int d = ni * 16 + l16;
                    u16x4 pk;
                    #pragma unroll
                    for (int r = 0; r < 4; ++r) pk[r] = f2bf(acc[mi][ni][r]);
                    *(u16x4*)(O + ((size_t)(b * NHEADS + h) * 64 + d) * T_SEQ + t) = pk;
                }
            }
        } else {
            const float qs = (z == 0) ? 0.125f : 1.0f;   // fold 1/sqrt(64) into Q (exact in bf16)
            #pragma unroll
            for (int mi = 0; mi < MI; ++mi) {
                #pragma unroll
                for (int r = 0; r < 4; ++r) {
                    const int m = m0 + wm * (MI * 16) + mi * 16 + quad * 4 + r;
                    const int b = m >> 11, t = m & (T_SEQ - 1);
                    const size_t rowoff = ((size_t)(b * NHEADS + h) * T_SEQ + t) * 64;
                    #pragma unroll
                    for (int ni = 0; ni < 2; ++ni) {
                        const int d = ni * 16 + l16;           // 0..31
                        const float c = cosp[t * 32 + d], s = sinp[t * 32 + d];
                        const float x1 = acc[mi][ni][r], x2 = acc[mi][ni + 2][r];
                        O[rowoff + d]      = f2bf((x1 * c - x2 * s) * qs);
                        O[rowoff + d + 32] = f2bf((x1 * s + x2 * c) * qs);
                    }
                }
            }
        }
    }
}

// ---------------- flash attention (causal), paired q-tiles, dbuf K/V, Vt input ----------------
#define LDA 66   // K/V LDS row pad (u16): b128 frag reads 2-way max (free)
#define LDP 68   // P LDS row pad (u16): scalar P writes conflict-free

__global__ __launch_bounds__(256) void attn_kernel(
    const unsigned short* __restrict__ Q,    // [bh][t][64] bf16, RoPE'd, pre-scaled 0.125
    const unsigned short* __restrict__ Kg,   // [bh][t][64] bf16, RoPE'd
    const unsigned short* __restrict__ Vt,   // [bh][d][t]  bf16 (transposed)
    unsigned short* __restrict__ Z)          // [m][h*64+d] bf16
{
    __shared__ unsigned short sK[2][64 * LDA];
    __shared__ unsigned short sV[2][64 * LDA];
    __shared__ unsigned short sP[4][2][16 * LDP];

    const int tid = threadIdx.x;
    const int wid = tid >> 6;
    const int lane = tid & 63;
    const int quad = lane >> 4;
    const int l16 = lane & 15;
    const int x = blockIdx.x;            // 0..15
    const int bh = blockIdx.y;           // 0..31
    const int qA = x, qB = 31 - x;       // paired q-tiles: work = 32-x, near-uniform
    const int jend = 31 - x;             // kv tiles 0..jend cover both

    const unsigned short* Qp = Q + (size_t)bh * T_SEQ * 64;
    const unsigned short* Kp = Kg + (size_t)bh * T_SEQ * 64;
    const unsigned short* Vp = Vt + (size_t)bh * 64 * T_SEQ;

    // Q A-frags: row = qt*64 + wid*16 + l16, k = ks*32 + quad*8
    short8 aqA[2], aqB[2];
    {
        const unsigned short* qr = Qp + (size_t)(qA * 64 + wid * 16 + l16) * 64 + quad * 8;
        aqA[0] = *(const short8*)(qr);
        aqA[1] = *(const short8*)(qr + 32);
        qr = Qp + (size_t)(qB * 64 + wid * 16 + l16) * 64 + quad * 8;
        aqB[0] = *(const short8*)(qr);
        aqB[1] = *(const short8*)(qr + 32);
    }

    f32x4 oA[4] = {}, oB[4] = {};
    float mA[4], lA[4], mB[4], lB[4];
    #pragma unroll
    for (int r = 0; r < 4; ++r) { mA[r] = -1e30f; lA[r] = 0.f; mB[r] = -1e30f; lB[r] = 0.f; }

    // staging: 2 u16x8 chunks each for K and V per thread
    const int sr0 = tid >> 3, scol0 = (tid & 7) * 8;   // rows 0..31
    const int sr1 = sr0 + 32;                          // rows 32..63
    u16x8 kreg0, kreg1, vreg0, vreg1;

    auto load_tile = [&](int j) {
        const unsigned short* Ks = Kp + (size_t)(j * 64) * 64;
        kreg0 = *(const u16x8*)(Ks + sr0 * 64 + scol0);
        kreg1 = *(const u16x8*)(Ks + sr1 * 64 + scol0);
        vreg0 = *(const u16x8*)(Vp + (size_t)sr0 * T_SEQ + j * 64 + scol0);
        vreg1 = *(const u16x8*)(Vp + (size_t)sr1 * T_SEQ + j * 64 + scol0);
    };
    auto store_tile = [&](int p) {
        *(u16x8*)&sK[p][sr0 * LDA + scol0] = kreg0;
        *(u16x8*)&sK[p][sr1 * LDA + scol0] = kreg1;
        *(u16x8*)&sV[p][sr0 * LDA + scol0] = vreg0;
        *(u16x8*)&sV[p][sr1 * LDA + scol0] = vreg1;
    };

    auto tile_softmax = [&](f32x4 (&s)[4], float (&m_i)[4], float (&l_i)[4], f32x4 (&o)[4],
                            bool msk, unsigned short* Pw) {
        if (msk) {
            #pragma unroll
            for (int nt = 0; nt < 4; ++nt) {
                const int col = nt * 16 + l16;
                #pragma unroll
                for (int r = 0; r < 4; ++r) {
                    const int row = wid * 16 + quad * 4 + r;
                    if (col > row) s[nt][r] = -1e30f;
                }
            }
        }
        float mloc[4] = {-1e30f, -1e30f, -1e30f, -1e30f};
        #pragma unroll
        for (int nt = 0; nt < 4; ++nt)
            #pragma unroll
            for (int r = 0; r < 4; ++r)
                mloc[r] = fmaxf(mloc[r], s[nt][r]);
        #pragma unroll
        for (int off = 8; off >= 1; off >>= 1)
            #pragma unroll
            for (int r = 0; r < 4; ++r)
                mloc[r] = fmaxf(mloc[r], __shfl_xor(mloc[r], off));
        float rs[4];
        #pragma unroll
        for (int r = 0; r < 4; ++r) {
            const float mnew = fmaxf(m_i[r], mloc[r]);
            const float al = __expf(m_i[r] - mnew);
            m_i[r] = mnew;
            l_i[r] *= al;
            #pragma unroll
            for (int dt = 0; dt < 4; ++dt) o[dt][r] *= al;
            rs[r] = 0.f;
            #pragma unroll
            for (int nt = 0; nt < 4; ++nt) {
                const float p = __expf(s[nt][r] - mnew);
                s[nt][r] = p;
                rs[r] += p;
            }
        }
        #pragma unroll
        for (int off = 8; off >= 1; off >>= 1)
            #pragma unroll
            for (int r = 0; r < 4; ++r)
                rs[r] += __shfl_xor(rs[r], off);
        #pragma unroll
        for (int r = 0; r < 4; ++r) l_i[r] += rs[r];
        #pragma unroll
        for (int nt = 0; nt < 4; ++nt)
            #pragma unroll
            for (int r = 0; r < 4; ++r)
                Pw[(quad * 4 + r) * LDP + nt * 16 + l16] = f2bf(s[nt][r]);
    };

    load_tile(0);
    store_tile(0);
    __syncthreads();

    for (int j = 0; j <= jend; ++j) {
        const int p = j & 1;
        if (j < jend) load_tile(j + 1);      // prefetch into regs, in flight during compute

        const bool doA = (j <= x);
        const unsigned short* bK = &sK[p][0];
        const unsigned short* bV = &sV[p][0];

        // QK^T for both tiles (K frags shared)
        f32x4 sAc[4] = {}, sBc[4] = {};
        #pragma unroll
        for (int nt = 0; nt < 4; ++nt) {
            const short8 kf0 = *(const short8*)&bK[(nt * 16 + l16) * LDA + quad * 8];
            const short8 kf1 = *(const short8*)&bK[(nt * 16 + l16) * LDA + 32 + quad * 8];
            if (doA) {
                sAc[nt] = __builtin_amdgcn_mfma_f32_16x16x32_bf16(aqA[0], kf0, sAc[nt], 0, 0, 0);
                sAc[nt] = __builtin_amdgcn_mfma_f32_16x16x32_bf16(aqA[1], kf1, sAc[nt], 0, 0, 0);
            }
            sBc[nt] = __builtin_amdgcn_mfma_f32_16x16x32_bf16(aqB[0], kf0, sBc[nt], 0, 0, 0);
            sBc[nt] = __builtin_amdgcn_mfma_f32_16x16x32_bf16(aqB[1], kf1, sBc[nt], 0, 0, 0);
        }

        unsigned short* PwA = &sP[wid][0][0];
        unsigned short* PwB = &sP[wid][1][0];
        if (doA) tile_softmax(sAc, mA, lA, oA, j == x, PwA);
        tile_softmax(sBc, mB, lB, oB, j == jend, PwB);
        asm volatile("s_waitcnt lgkmcnt(0)" ::: "memory");

        short8 pfA0, pfA1, pfB0, pfB1;
        if (doA) {
            pfA0 = *(const short8*)&PwA[l16 * LDP + quad * 8];
            pfA1 = *(const short8*)&PwA[l16 * LDP + 32 + quad * 8];
        }
        pfB0 = *(const short8*)&PwB[l16 * LDP + quad * 8];
        pfB1 = *(const short8*)&PwB[l16 * LDP + 32 + quad * 8];

        // O += P @ V  (V frags shared between tiles)
        #pragma unroll
        for (int dt = 0; dt < 4; ++dt) {
            const short8 vf0 = *(const short8*)&bV[(dt * 16 + l16) * LDA + quad * 8];
            const short8 vf1 = *(const short8*)&bV[(dt * 16 + l16) * LDA + 32 + quad * 8];
            if (doA) {
                oA[dt] = __builtin_amdgcn_mfma_f32_16x16x32_bf16(pfA0, vf0, oA[dt], 0, 0, 0);
                oA[dt] = __builtin_amdgcn_mfma_f32_16x16x32_bf16(pfA1, vf1, oA[dt], 0, 0, 0);
            }
            oB[dt] = __builtin_amdgcn_mfma_f32_16x16x32_bf16(pfB0, vf0, oB[dt], 0, 0, 0);
            oB[dt] = __builtin_amdgcn_mfma_f32_16x16x32_bf16(pfB1, vf1, oB[dt], 0, 0, 0);
        }

        if (j < jend) store_tile(1 - p);
        __syncthreads();
    }

    // epilogue
    const int h = bh & 15, b = bh >> 4;
    #pragma unroll
    for (int dt = 0; dt < 4; ++dt)
        #pragma unroll
        for (int r = 0; r < 4; ++r) {
            const int rowA = qA * 64 + wid * 16 + quad * 4 + r;
            const int rowB = qB * 64 + wid * 16 + quad * 4 + r;
            const int col = h * 64 + dt * 16 + l16;
            Z[((size_t)b * T_SEQ + rowA) * D_MODEL + col] = f2bf(oA[dt][r] / lA[r]);
            Z[((size_t)b * T_SEQ + rowB) * D_MODEL + col] = f2bf(oB[dt][r] / lB[r]);
        }
}

// ---------------- launcher ----------------
extern "C" void kernel_launch(void* const* d_in, const int* in_sizes, int n_in,
                              void* d_out, int out_size, void* d_ws, size_t ws_size,
                              hipStream_t stream) {
    const float* x    = (const float*)d_in[0];
    const float* cosp = (const float*)d_in[1];
    const float* sinp = (const float*)d_in[2];
    const float* Wq   = (const float*)d_in[3];
    const float* Wk   = (const float*)d_in[4];
    const float* Wv   = (const float*)d_in[5];
    const float* Wo   = (const float*)d_in[6];

    char* w = (char*)d_ws;
    unsigned short* xb  = (unsigned short*)w; w += (size_t)M_TOT * D_MODEL * 2;    // 8 MB
    unsigned short* wt  = (unsigned short*)w; w += (size_t)4 * D_MODEL * D_MODEL * 2; // 8 MB (q,k,v,o)
    unsigned short* Qb  = (unsigned short*)w; w += (size_t)M_TOT * D_MODEL * 2;    // 8 MB
    unsigned short* Kb  = (unsigned short*)w; w += (size_t)M_TOT * D_MODEL * 2;
    unsigned short* Vtb = (unsigned short*)w; w += (size_t)M_TOT * D_MODEL * 2;    // [bh][d][t]
    unsigned short* Zb  = (unsigned short*)w; w += (size_t)M_TOT * D_MODEL * 2;

    convert_x_kernel<<<(M_TOT * D_MODEL) / 1024, 256, 0, stream>>>(x, xb);
    transpose_w_kernel<<<dim3(16, 16, 4), 256, 0, stream>>>(Wq, Wk, Wv, Wo, wt);

    // fused QKV projection; epilogue: z=0 Q(RoPE,*0.125), z=1 K(RoPE), z=2 V(transposed)
    gemm_kernel<4, 1><<<dim3(M_TOT / 128, D_MODEL / 128, 3), 256, 0, stream>>>(
        xb, wt, (void*)Qb, cosp, sinp);

    attn_kernel<<<dim3(16, 32), 256, 0, stream>>>(Qb, Kb, Vtb, Zb);

    // out projection -> fp32 d_out
    gemm_kernel<2, 0><<<dim3(M_TOT / 64, D_MODEL / 128, 1), 256, 0, stream>>>(
        Zb, wt + (size_t)3 * D_MODEL * D_MODEL, d_out, nullptr, nullptr);
}

// Round 5
// 313.451 us; speedup vs baseline: 1.1637x; 1.0548x over previous
//
#include <hip/hip_runtime.h>

typedef __attribute__((ext_vector_type(4))) float f32x4;
typedef __attribute__((ext_vector_type(8))) short short8;
typedef __attribute__((ext_vector_type(8))) unsigned short u16x8;
typedef __attribute__((ext_vector_type(4))) unsigned short u16x4;

#define D_MODEL 1024
#define NHEADS 16
#define T_SEQ 2048
#define M_TOT 4096   // B*T

__device__ __forceinline__ unsigned short f2bf(float f) {
    union { float f; unsigned int u; } v; v.f = f;
    return (unsigned short)((v.u + 0x7fffu + ((v.u >> 16) & 1u)) >> 16);
}

// ---- 16-lane group all-reduce at VALU speed (DPP), shfl fallback ----
// Steps: quad_perm(1,0,3,2)=0xB1, quad_perm(2,3,0,1)=0x4E, ROW_HALF_MIRROR=0x141,
// ROW_MIRROR=0x140. Valid butterfly over each 16-lane row (all lanes active).
#if __has_builtin(__builtin_amdgcn_update_dpp)
__device__ __forceinline__ float dpp_bcast_f(float v, int ctrl_dummy) { return v; }
#define DPP_STEP(v, ctrl, OP)                                              \
    {                                                                      \
        union { float f; int i; } a_, b_;                                  \
        a_.f = (v);                                                        \
        b_.i = __builtin_amdgcn_update_dpp(a_.i, a_.i, ctrl, 0xf, 0xf, false); \
        (v) = OP((v), b_.f);                                               \
    }
__device__ __forceinline__ float rowmax16(float v) {
    DPP_STEP(v, 0xB1, fmaxf); DPP_STEP(v, 0x4E, fmaxf);
    DPP_STEP(v, 0x141, fmaxf); DPP_STEP(v, 0x140, fmaxf);
    return v;
}
__device__ __forceinline__ float rowsum16(float v) {
    #define FADD_(a, b) ((a) + (b))
    DPP_STEP(v, 0xB1, FADD_); DPP_STEP(v, 0x4E, FADD_);
    DPP_STEP(v, 0x141, FADD_); DPP_STEP(v, 0x140, FADD_);
    #undef FADD_
    return v;
}
#else
__device__ __forceinline__ float rowmax16(float v) {
    for (int off = 8; off >= 1; off >>= 1) v = fmaxf(v, __shfl_xor(v, off));
    return v;
}
__device__ __forceinline__ float rowsum16(float v) {
    for (int off = 8; off >= 1; off >>= 1) v += __shfl_xor(v, off);
    return v;
}
#endif

// ---------------- convert x fp32 -> bf16 ----------------
__global__ __launch_bounds__(256) void convert_x_kernel(const float* __restrict__ X,
                                                        unsigned short* __restrict__ Xb) {
    const int i = (blockIdx.x * 256 + threadIdx.x) * 4;
    const float4 v = *(const float4*)(X + i);
    u16x4 r;
    r.x = f2bf(v.x); r.y = f2bf(v.y); r.z = f2bf(v.z); r.w = f2bf(v.w);
    *(u16x4*)(Xb + i) = r;
}

// ---------------- 4x W [k][n] fp32 -> Wt [n][k] bf16, batched over z ----------------
__global__ __launch_bounds__(256) void transpose_w_kernel(const float* __restrict__ W0,
                                                          const float* __restrict__ W1,
                                                          const float* __restrict__ W2,
                                                          const float* __restrict__ W3,
                                                          unsigned short* __restrict__ Wt0) {
    __shared__ float tile[64][65];
    const int z = blockIdx.z;
    const float* W = (z == 0) ? W0 : (z == 1) ? W1 : (z == 2) ? W2 : W3;
    unsigned short* Wt = Wt0 + (size_t)z * D_MODEL * D_MODEL;
    const int n0 = blockIdx.x * 64, k0 = blockIdx.y * 64;
    for (int i = threadIdx.x; i < 4096; i += 256) {
        const int r = i >> 6, c = i & 63;
        tile[r][c] = W[(size_t)(k0 + r) * D_MODEL + n0 + c];
    }
    __syncthreads();
    for (int i = threadIdx.x; i < 4096; i += 256) {
        const int r = i >> 6, c = i & 63;  // r: n-local, c: k-local
        Wt[(size_t)(n0 + r) * D_MODEL + k0 + c] = f2bf(tile[c][r]);
    }
}

// ---------------- GEMM: C = A[M][1024] @ W, with Wt[n][k] pre-transposed ----------------
// OUTMODE 0: fp32 row-major C (out projection)
// OUTMODE 1: z=0 Q (RoPE, pre-scaled 0.125), z=1 K (RoPE), z=2 V (transposed [bh][d][t])
#define TN_G 128
#define BK_G 32
#define BKP_G 36

template<int MI, int OUTMODE>
__global__ __launch_bounds__(256) void gemm_kernel(
    const unsigned short* __restrict__ A,
    const unsigned short* __restrict__ Bt0,
    void* __restrict__ Cout0,
    const float* __restrict__ cosp,
    const float* __restrict__ sinp)
{
    constexpr int TMc = MI * 32;
    constexpr int NA = (TMc * 4) / 256;
    __shared__ unsigned short sA[TMc * BKP_G];
    __shared__ unsigned short sB[TN_G * BKP_G];

    const int tid = threadIdx.x;
    const int wid = tid >> 6;
    const int lane = tid & 63;
    const int quad = lane >> 4;
    const int l16 = lane & 15;
    const int wm = wid >> 1, wn = wid & 1;
    const int m0 = blockIdx.x * TMc, n0 = blockIdx.y * TN_G;
    const int z = blockIdx.z;
    const unsigned short* Bt = Bt0 + (size_t)z * D_MODEL * D_MODEL;

    f32x4 acc[MI][4] = {};

    for (int k0 = 0; k0 < D_MODEL; k0 += BK_G) {
        u16x8 av[NA], bv[2];
        #pragma unroll
        for (int i = 0; i < NA; ++i) {
            const int c = tid + i * 256, r = c >> 2, sg = (c & 3) * 8;
            av[i] = *(const u16x8*)(A + (size_t)(m0 + r) * D_MODEL + k0 + sg);
        }
        #pragma unroll
        for (int i = 0; i < 2; ++i) {
            const int c = tid + i * 256, r = c >> 2, sg = (c & 3) * 8;
            bv[i] = *(const u16x8*)(Bt + (size_t)(n0 + r) * D_MODEL + k0 + sg);
        }
        __syncthreads();
        #pragma unroll
        for (int i = 0; i < NA; ++i) {
            const int c = tid + i * 256, r = c >> 2, sg = (c & 3) * 8;
            *(u16x8*)&sA[r * BKP_G + sg] = av[i];
        }
        #pragma unroll
        for (int i = 0; i < 2; ++i) {
            const int c = tid + i * 256, r = c >> 2, sg = (c & 3) * 8;
            *(u16x8*)&sB[r * BKP_G + sg] = bv[i];
        }
        __syncthreads();

        short8 af[MI], bf[4];
        #pragma unroll
        for (int i = 0; i < MI; ++i)
            af[i] = *(const short8*)&sA[(wm * (MI * 16) + i * 16 + l16) * BKP_G + quad * 8];
        #pragma unroll
        for (int i = 0; i < 4; ++i)
            bf[i] = *(const short8*)&sB[(wn * 64 + i * 16 + l16) * BKP_G + quad * 8];
        #pragma unroll
        for (int mi = 0; mi < MI; ++mi)
            #pragma unroll
            for (int ni = 0; ni < 4; ++ni)
                acc[mi][ni] = __builtin_amdgcn_mfma_f32_16x16x32_bf16(af[mi], bf[ni], acc[mi][ni], 0, 0, 0);
    }

    if constexpr (OUTMODE == 0) {
        float* C = (float*)Cout0;
        #pragma unroll
        for (int mi = 0; mi < MI; ++mi) {
            const int mb = m0 + wm * (MI * 16) + mi * 16 + quad * 4;
            #pragma unroll
            for (int ni = 0; ni < 4; ++ni) {
                const int n = n0 + wn * 64 + ni * 16 + l16;
                #pragma unroll
                for (int r = 0; r < 4; ++r)
                    C[(size_t)(mb + r) * D_MODEL + n] = acc[mi][ni][r];
            }
        }
    } else {
        unsigned short* O = (unsigned short*)Cout0 + (size_t)z * M_TOT * D_MODEL;
        const int h = (n0 + wn * 64) >> 6;   // each wave's 64 cols = exactly one head
        if (z == 2) {
            // V: write transposed Vt[bh][d][t], packed u16x4 over 4 consecutive t
            #pragma unroll
            for (int mi = 0; mi < MI; ++mi) {
                const int mb = m0 + wm * (MI * 16) + mi * 16 + quad * 4;
                const int b = mb >> 11, t = mb & (T_SEQ - 1);
                #pragma unroll
                for (int ni = 0; ni < 4; ++ni) {
                    const int d = ni * 16 + l16;
                    u16x4 pk;
                    #pragma unroll
                    for (int r = 0; r < 4; ++r) pk[r] = f2bf(acc[mi][ni][r]);
                    *(u16x4*)(O + ((size_t)(b * NHEADS + h) * 64 + d) * T_SEQ + t) = pk;
                }
            }
        } else {
            const float qs = (z == 0) ? 0.125f : 1.0f;   // fold 1/sqrt(64) into Q (exact in bf16)
            #pragma unroll
            for (int mi = 0; mi < MI; ++mi) {
                #pragma unroll
                for (int r = 0; r < 4; ++r) {
                    const int m = m0 + wm * (MI * 16) + mi * 16 + quad * 4 + r;
                    const int b = m >> 11, t = m & (T_SEQ - 1);
                    const size_t rowoff = ((size_t)(b * NHEADS + h) * T_SEQ + t) * 64;
                    #pragma unroll
                    for (int ni = 0; ni < 2; ++ni) {
                        const int d = ni * 16 + l16;           // 0..31
                        const float c = cosp[t * 32 + d], s = sinp[t * 32 + d];
                        const float x1 = acc[mi][ni][r], x2 = acc[mi][ni + 2][r];
                        O[rowoff + d]      = f2bf((x1 * c - x2 * s) * qs);
                        O[rowoff + d + 32] = f2bf((x1 * s + x2 * c) * qs);
                    }
                }
            }
        }
    }
}

// ---------------- flash attention (causal): R2-proven online softmax, cheaper reductions ----------------
// vs R2: (1) max butterfly on DPP (VALU latency) instead of ds_permute; (2) l kept as
// per-lane partials, reduced ONCE in epilogue (value identical modulo fp association).
#define LDA 66   // K/V LDS row pad (u16): b128 frag reads 2-way max (free)
#define LDP 68   // P LDS row pad (u16): scalar P writes conflict-free

__global__ __launch_bounds__(256) void attn_kernel(
    const unsigned short* __restrict__ Q,    // [bh][t][64] bf16, RoPE'd, pre-scaled 0.125
    const unsigned short* __restrict__ Kg,   // [bh][t][64] bf16, RoPE'd
    const unsigned short* __restrict__ Vt,   // [bh][d][t]  bf16 (transposed)
    unsigned short* __restrict__ Z)          // [m][h*64+d] bf16
{
    __shared__ unsigned short sK[2][64 * LDA];
    __shared__ unsigned short sV[2][64 * LDA];
    __shared__ unsigned short sP[4][2][16 * LDP];

    const int tid = threadIdx.x;
    const int wid = tid >> 6;
    const int lane = tid & 63;
    const int quad = lane >> 4;
    const int l16 = lane & 15;
    const int x = blockIdx.x;            // 0..15
    const int bh = blockIdx.y;           // 0..31
    const int qA = x, qB = 31 - x;       // paired q-tiles: work = 32-x, near-uniform
    const int jend = 31 - x;             // kv tiles 0..jend cover both

    const unsigned short* Qp = Q + (size_t)bh * T_SEQ * 64;
    const unsigned short* Kp = Kg + (size_t)bh * T_SEQ * 64;
    const unsigned short* Vp = Vt + (size_t)bh * 64 * T_SEQ;

    // Q A-frags: row = qt*64 + wid*16 + l16, k = ks*32 + quad*8
    short8 aqA[2], aqB[2];
    {
        const unsigned short* qr = Qp + (size_t)(qA * 64 + wid * 16 + l16) * 64 + quad * 8;
        aqA[0] = *(const short8*)(qr);
        aqA[1] = *(const short8*)(qr + 32);
        qr = Qp + (size_t)(qB * 64 + wid * 16 + l16) * 64 + quad * 8;
        aqB[0] = *(const short8*)(qr);
        aqB[1] = *(const short8*)(qr + 32);
    }

    f32x4 oA[4] = {}, oB[4] = {};
    float mA[4], lA[4], mB[4], lB[4];
    #pragma unroll
    for (int r = 0; r < 4; ++r) { mA[r] = -1e30f; lA[r] = 0.f; mB[r] = -1e30f; lB[r] = 0.f; }

    // staging: 2 u16x8 chunks each for K and V per thread
    const int sr0 = tid >> 3, scol0 = (tid & 7) * 8;   // rows 0..31
    const int sr1 = sr0 + 32;                          // rows 32..63
    u16x8 kreg0, kreg1, vreg0, vreg1;

    auto load_tile = [&](int j) {
        const unsigned short* Ks = Kp + (size_t)(j * 64) * 64;
        kreg0 = *(const u16x8*)(Ks + sr0 * 64 + scol0);
        kreg1 = *(const u16x8*)(Ks + sr1 * 64 + scol0);
        vreg0 = *(const u16x8*)(Vp + (size_t)sr0 * T_SEQ + j * 64 + scol0);
        vreg1 = *(const u16x8*)(Vp + (size_t)sr1 * T_SEQ + j * 64 + scol0);
    };
    auto store_tile = [&](int p) {
        *(u16x8*)&sK[p][sr0 * LDA + scol0] = kreg0;
        *(u16x8*)&sK[p][sr1 * LDA + scol0] = kreg1;
        *(u16x8*)&sV[p][sr0 * LDA + scol0] = vreg0;
        *(u16x8*)&sV[p][sr1 * LDA + scol0] = vreg1;
    };

    // online softmax (R2 numerics): mask -> DPP row max -> alpha rescale -> exp ->
    // per-lane l partial -> P write. No in-loop sum reduction.
    auto tile_softmax = [&](f32x4 (&s)[4], float (&m_i)[4], float (&l_i)[4], f32x4 (&o)[4],
                            bool msk, unsigned short* Pw) {
        if (msk) {
            #pragma unroll
            for (int nt = 0; nt < 4; ++nt) {
                const int col = nt * 16 + l16;
                #pragma unroll
                for (int r = 0; r < 4; ++r) {
                    const int row = wid * 16 + quad * 4 + r;
                    if (col > row) s[nt][r] = -1e30f;
                }
            }
        }
        float mloc[4];
        #pragma unroll
        for (int r = 0; r < 4; ++r)
            mloc[r] = fmaxf(fmaxf(s[0][r], s[1][r]), fmaxf(s[2][r], s[3][r]));
        #pragma unroll
        for (int r = 0; r < 4; ++r) mloc[r] = rowmax16(mloc[r]);
        #pragma unroll
        for (int r = 0; r < 4; ++r) {
            const float mnew = fmaxf(m_i[r], mloc[r]);
            const float al = __expf(m_i[r] - mnew);
            m_i[r] = mnew;
            float rs = 0.f;
            #pragma unroll
            for (int nt = 0; nt < 4; ++nt) {
                const float p = __expf(s[nt][r] - mnew);
                s[nt][r] = p;
                rs += p;
            }
            l_i[r] = l_i[r] * al + rs;   // per-lane partial
            #pragma unroll
            for (int dt = 0; dt < 4; ++dt) o[dt][r] *= al;
            #pragma unroll
            for (int nt = 0; nt < 4; ++nt)
                Pw[(quad * 4 + r) * LDP + nt * 16 + l16] = f2bf(s[nt][r]);
        }
    };

    load_tile(0);
    store_tile(0);
    __syncthreads();

    for (int j = 0; j <= jend; ++j) {
        const int p = j & 1;
        if (j < jend) load_tile(j + 1);      // prefetch into regs, in flight during compute

        const bool doA = (j <= x);
        const unsigned short* bK = &sK[p][0];
        const unsigned short* bV = &sV[p][0];

        // QK^T for both tiles (K frags shared)
        f32x4 sAc[4] = {}, sBc[4] = {};
        #pragma unroll
        for (int nt = 0; nt < 4; ++nt) {
            const short8 kf0 = *(const short8*)&bK[(nt * 16 + l16) * LDA + quad * 8];
            const short8 kf1 = *(const short8*)&bK[(nt * 16 + l16) * LDA + 32 + quad * 8];
            if (doA) {
                sAc[nt] = __builtin_amdgcn_mfma_f32_16x16x32_bf16(aqA[0], kf0, sAc[nt], 0, 0, 0);
                sAc[nt] = __builtin_amdgcn_mfma_f32_16x16x32_bf16(aqA[1], kf1, sAc[nt], 0, 0, 0);
            }
            sBc[nt] = __builtin_amdgcn_mfma_f32_16x16x32_bf16(aqB[0], kf0, sBc[nt], 0, 0, 0);
            sBc[nt] = __builtin_amdgcn_mfma_f32_16x16x32_bf16(aqB[1], kf1, sBc[nt], 0, 0, 0);
        }

        unsigned short* PwA = &sP[wid][0][0];
        unsigned short* PwB = &sP[wid][1][0];
        if (doA) tile_softmax(sAc, mA, lA, oA, j == x, PwA);
        tile_softmax(sBc, mB, lB, oB, j == jend, PwB);
        asm volatile("s_waitcnt lgkmcnt(0)" ::: "memory");

        short8 pfA0 = {}, pfA1 = {}, pfB0, pfB1;
        if (doA) {
            pfA0 = *(const short8*)&PwA[l16 * LDP + quad * 8];
            pfA1 = *(const short8*)&PwA[l16 * LDP + 32 + quad * 8];
        }
        pfB0 = *(const short8*)&PwB[l16 * LDP + quad * 8];
        pfB1 = *(const short8*)&PwB[l16 * LDP + 32 + quad * 8];

        // O += P @ V  (V frags shared between tiles)
        #pragma unroll
        for (int dt = 0; dt < 4; ++dt) {
            const short8 vf0 = *(const short8*)&bV[(dt * 16 + l16) * LDA + quad * 8];
            const short8 vf1 = *(const short8*)&bV[(dt * 16 + l16) * LDA + 32 + quad * 8];
            if (doA) {
                oA[dt] = __builtin_amdgcn_mfma_f32_16x16x32_bf16(pfA0, vf0, oA[dt], 0, 0, 0);
                oA[dt] = __builtin_amdgcn_mfma_f32_16x16x32_bf16(pfA1, vf1, oA[dt], 0, 0, 0);
            }
            oB[dt] = __builtin_amdgcn_mfma_f32_16x16x32_bf16(pfB0, vf0, oB[dt], 0, 0, 0);
            oB[dt] = __builtin_amdgcn_mfma_f32_16x16x32_bf16(pfB1, vf1, oB[dt], 0, 0, 0);
        }

        if (j < jend) store_tile(1 - p);
        __syncthreads();
    }

    // single cross-lane row-sum reduction of the per-lane l partials
    #pragma unroll
    for (int r = 0; r < 4; ++r) {
        lA[r] = rowsum16(lA[r]);
        lB[r] = rowsum16(lB[r]);
    }

    // epilogue: normalize and write
    const int h = bh & 15, b = bh >> 4;
    #pragma unroll
    for (int r = 0; r < 4; ++r) { lA[r] = 1.f / lA[r]; lB[r] = 1.f / lB[r]; }
    #pragma unroll
    for (int dt = 0; dt < 4; ++dt)
        #pragma unroll
        for (int r = 0; r < 4; ++r) {
            const int rowA = qA * 64 + wid * 16 + quad * 4 + r;
            const int rowB = qB * 64 + wid * 16 + quad * 4 + r;
            const int col = h * 64 + dt * 16 + l16;
            Z[((size_t)b * T_SEQ + rowA) * D_MODEL + col] = f2bf(oA[dt][r] * lA[r]);
            Z[((size_t)b * T_SEQ + rowB) * D_MODEL + col] = f2bf(oB[dt][r] * lB[r]);
        }
}

// ---------------- launcher ----------------
extern "C" void kernel_launch(void* const* d_in, const int* in_sizes, int n_in,
                              void* d_out, int out_size, void* d_ws, size_t ws_size,
                              hipStream_t stream) {
    const float* x    = (const float*)d_in[0];
    const float* cosp = (const float*)d_in[1];
    const float* sinp = (const float*)d_in[2];
    const float* Wq   = (const float*)d_in[3];
    const float* Wk   = (const float*)d_in[4];
    const float* Wv   = (const float*)d_in[5];
    const float* Wo   = (const float*)d_in[6];

    char* w = (char*)d_ws;
    unsigned short* xb  = (unsigned short*)w; w += (size_t)M_TOT * D_MODEL * 2;    // 8 MB
    unsigned short* wt  = (unsigned short*)w; w += (size_t)4 * D_MODEL * D_MODEL * 2; // 8 MB (q,k,v,o)
    unsigned short* Qb  = (unsigned short*)w; w += (size_t)M_TOT * D_MODEL * 2;    // 8 MB
    unsigned short* Kb  = (unsigned short*)w; w += (size_t)M_TOT * D_MODEL * 2;
    unsigned short* Vtb = (unsigned short*)w; w += (size_t)M_TOT * D_MODEL * 2;    // [bh][d][t]
    unsigned short* Zb  = (unsigned short*)w; w += (size_t)M_TOT * D_MODEL * 2;

    convert_x_kernel<<<(M_TOT * D_MODEL) / 1024, 256, 0, stream>>>(x, xb);
    transpose_w_kernel<<<dim3(16, 16, 4), 256, 0, stream>>>(Wq, Wk, Wv, Wo, wt);

    // fused QKV projection; epilogue: z=0 Q(RoPE,*0.125), z=1 K(RoPE), z=2 V(transposed)
    gemm_kernel<4, 1><<<dim3(M_TOT / 128, D_MODEL / 128, 3), 256, 0, stream>>>(
        xb, wt, (void*)Qb, cosp, sinp);

    attn_kernel<<<dim3(16, 32), 256, 0, stream>>>(Qb, Kb, Vtb, Zb);

    // out projection -> fp32 d_out
    gemm_kernel<2, 0><<<dim3(M_TOT / 64, D_MODEL / 128, 1), 256, 0, stream>>>(
        Zb, wt + (size_t)3 * D_MODEL * D_MODEL, d_out, nullptr, nullptr);
}